// Round 8
// baseline (97.690 us; speedup 1.0000x reference)
//
#include <hip/hip_runtime.h>
#include <hip/hip_bf16.h>

// Problem constants
#define NB    65536      // batch rows
#define ND    1024       // feature dim (K)
#define NT    64         // trees (N)
#define NKS   32         // K-steps of 32 (MFMA K)
#define WROWS 16         // rows per wave
#define ROWS  64         // rows per block (4 waves)

typedef __attribute__((ext_vector_type(8))) short bf16x8;
typedef __attribute__((ext_vector_type(4))) float f32x4;

__device__ __forceinline__ short f2bf_s(float f) {
    __hip_bfloat16 h = __float2bfloat16(f);
    return __builtin_bit_cast(short, h);
}

// ---- prep: feature_selectors [64][1024] f32 -> bf16 in d_ws (L2-resident B) ----
__global__ __launch_bounds__(256) void prep_kernel(const float* __restrict__ F,
                                                   __hip_bfloat16* __restrict__ Fb) {
    int idx = blockIdx.x * 256 + threadIdx.x;  // 256 blocks -> 65536 elements
    Fb[idx] = __float2bfloat16(F[idx]);
}

// ---- main: NO LDS, NO barriers. Each wave = independent stream over 16 rows,
// all 64 trees, K=1024. A-fragments load straight from global (lane (c,g) owns
// x[row=c][k=g*8..+8] -- 16 rows x 128B contiguous per wave per K-step).
// Manual 4-deep register pipeline on A; B rides on full unroll from L2.
template <bool PREPPED>
__global__ __launch_bounds__(256, 4) void node_main(const float* __restrict__ x,
                                                    const void* __restrict__ Fv,
                                                    const float* __restrict__ thr,
                                                    const float* __restrict__ lw,
                                                    float* __restrict__ out) {
    const int tid  = threadIdx.x;
    const int w    = tid >> 6;       // wave id
    const int lane = tid & 63;
    const int c    = lane & 15;      // MFMA 16-index: batch row (A) / tree col (B)
    const int g    = lane >> 4;      // k-group
    const long waveRow = (long)blockIdx.x * ROWS + (long)w * WROWS;
    const float* xlane = x + (waveRow + c) * ND + g * 8;   // this lane's A stream

    // per-lane tree constants: this lane's trees are {c, c+16, c+32, c+48}
    float thr_t[4], d0[4], d1[4], s0 = 0.f, s1 = 0.f;
#pragma unroll
    for (int nt = 0; nt < 4; ++nt) {
        const int t = nt * 16 + c;
        thr_t[nt] = thr[t];
        const float w00 = lw[t * 4 + 0], w01 = lw[t * 4 + 1];
        const float w10 = lw[t * 4 + 2], w11 = lw[t * 4 + 3];
        d0[nt] = w00 - w10;  d1[nt] = w01 - w11;
        s0 += w10;           s1 += w11;
    }

    const __hip_bfloat16* Fb = (const __hip_bfloat16*)Fv;
    const float*          Ff = (const float*)Fv;

    f32x4 acc[4];
#pragma unroll
    for (int nt = 0; nt < 4; ++nt) acc[nt] = (f32x4){0.f, 0.f, 0.f, 0.f};

    // 4-deep A pipeline (static slot indices via full unroll -- rule #20)
    f32x4 pa0[4], pa1[4];
#pragma unroll
    for (int s = 0; s < 4; ++s) {
        pa0[s] = *(const f32x4*)(xlane + s * 32);
        pa1[s] = *(const f32x4*)(xlane + s * 32 + 4);
    }

#pragma unroll
    for (int ks = 0; ks < NKS; ++ks) {
        const int slot = ks & 3;
        // cvt current A fragment
        f32x4 a0 = pa0[slot], a1 = pa1[slot];
        bf16x8 af;
        af[0] = f2bf_s(a0[0]); af[1] = f2bf_s(a0[1]);
        af[2] = f2bf_s(a0[2]); af[3] = f2bf_s(a0[3]);
        af[4] = f2bf_s(a1[0]); af[5] = f2bf_s(a1[1]);
        af[6] = f2bf_s(a1[2]); af[7] = f2bf_s(a1[3]);
        // refill slot with K-step ks+4 (stays in flight across the 4 MFMAs below
        // plus three more K-steps before its first use)
        if (ks + 4 < NKS) {
            pa0[slot] = *(const f32x4*)(xlane + (ks + 4) * 32);
            pa1[slot] = *(const f32x4*)(xlane + (ks + 4) * 32 + 4);
        }
        // B (L2-resident) + MFMA, 4 tree-tiles
#pragma unroll
        for (int nt = 0; nt < 4; ++nt) {
            const long boff = (long)(nt * 16 + c) * ND + ks * 32 + g * 8;
            bf16x8 bfrag;
            if constexpr (PREPPED) {
                bfrag = *(const bf16x8*)(Fb + boff);
            } else {
                f32x4 b0 = *(const f32x4*)(Ff + boff);
                f32x4 b1 = *(const f32x4*)(Ff + boff + 4);
                bfrag[0] = f2bf_s(b0[0]); bfrag[1] = f2bf_s(b0[1]);
                bfrag[2] = f2bf_s(b0[2]); bfrag[3] = f2bf_s(b0[3]);
                bfrag[4] = f2bf_s(b1[0]); bfrag[5] = f2bf_s(b1[1]);
                bfrag[6] = f2bf_s(b1[2]); bfrag[7] = f2bf_s(b1[3]);
            }
            acc[nt] = __builtin_amdgcn_mfma_f32_16x16x32_bf16(af, bfrag, acc[nt], 0, 0, 0);
        }
    }

    // ---- epilogue (wave-local, proven R4): sigmoid + leaf combine + 16-lane reduce ----
    // D layout: col = c (tree-within-tile), row = g*4 + reg (batch row within 16)
#pragma unroll
    for (int reg = 0; reg < 4; ++reg) {
        float o0 = s0, o1 = s1;
#pragma unroll
        for (int nt = 0; nt < 4; ++nt) {
            const float logit = acc[nt][reg] - thr_t[nt];
            const float p = 1.0f / (1.0f + __expf(-logit));
            o0 += p * d0[nt];
            o1 += p * d1[nt];
        }
#pragma unroll
        for (int m = 1; m < 16; m <<= 1) {   // butterfly over the 16 c-lanes
            o0 += __shfl_xor(o0, m, 64);
            o1 += __shfl_xor(o1, m, 64);
        }
        if (c == 0) {
            const long row = waveRow + g * 4 + reg;
            *(float2*)(out + row * 2) = make_float2(o0, o1);
        }
    }
}

extern "C" void kernel_launch(void* const* d_in, const int* in_sizes, int n_in,
                              void* d_out, int out_size, void* d_ws, size_t ws_size,
                              hipStream_t stream) {
    const float* x   = (const float*)d_in[0];
    const float* fs  = (const float*)d_in[1];
    const float* thr = (const float*)d_in[2];
    const float* lw  = (const float*)d_in[3];
    float* out = (float*)d_out;
    (void)in_sizes; (void)n_in; (void)out_size;

    const size_t FB_BYTES = (size_t)NT * ND * sizeof(__hip_bfloat16);  // 128 KB
    if (ws_size >= FB_BYTES) {
        __hip_bfloat16* Fb = (__hip_bfloat16*)d_ws;
        prep_kernel<<<256, 256, 0, stream>>>(fs, Fb);
        node_main<true><<<NB / ROWS, 256, 0, stream>>>(x, (const void*)Fb, thr, lw, out);
    } else {
        node_main<false><<<NB / ROWS, 256, 0, stream>>>(x, (const void*)fs, thr, lw, out);
    }
}